// Round 11
// baseline (752.931 us; speedup 1.0000x reference)
//
#include <hip/hip_runtime.h>
#include <hip/hip_fp16.h>

#define L_ 13
#define B_ 32
#define S_ 128
#define H_ 768
#define NU 32
#define GG 64
#define TU 96
#define LN_EPS 1e-3f
#define SEQ_ST 68
#define WK_ST 100
#define XPH_ST 100
#define K1f 1.4426950408889634f   // log2(e)
#define K2f 2.8853900817779268f   // 2*log2(e)

// DPP controls
#define DPP_X1  0xB1
#define DPP_X2  0x4E
#define DPP_X7  0x141
#define DPP_X15 0x140

// LDS float-slot offsets
#define OFF_WK   8704                       // seqb: 128*68 = 8704 floats
#define OFF_XPH  (OFF_WK + 6400)            // wk2: 2*32*100 half2 = 6400 floats
#define OFF_XT2  (OFF_XPH + 12800)          // xph: 2*128*100 halves = 12800 floats  [R10 bug: was 6400]
#define OFF_HB   (OFF_XT2 + 3456)           // xt2all: 6*576 half2 = 3456 floats
#define OFF_FLG  (OFF_HB + 64)
#define SMEM_FLOATS (OFF_FLG + 32)

typedef float v2f __attribute__((ext_vector_type(2)));
typedef _Float16 h2t __attribute__((ext_vector_type(2)));
typedef unsigned int uv2 __attribute__((ext_vector_type(2)));

union F4H8 { float4 f4; __half2 hh[4]; h2t h[4]; };
union FH2  { float f; __half2 hh; h2t h; };
union F2H2 { float2 f2; __half2 hh[2]; };

__device__ __forceinline__ void pkfma(v2f& a, v2f x, v2f w) {
    asm("v_pk_fma_f32 %0, %1, %2, %0" : "+v"(a) : "v"(x), "v"(w));
}
template <int CTRL>
__device__ __forceinline__ float dppf(float x) {
    return __int_as_float(__builtin_amdgcn_update_dpp(
        0, __float_as_int(x), CTRL, 0xF, 0xF, true));
}
__device__ __forceinline__ float pairsum16(float x) {
#if __has_builtin(__builtin_amdgcn_permlane16_swap)
    uv2 s = __builtin_amdgcn_permlane16_swap(
        __float_as_uint(x), __float_as_uint(x), false, false);
    return __uint_as_float(s.x) + __uint_as_float(s.y);
#else
    return x + __shfl_xor(x, 16);
#endif
}
__device__ __forceinline__ int chunk_of(int r) {
    return (r < 64) ? ((63 - r) >> 3) : ((r - 64) >> 3);
}
__device__ __forceinline__ void poll_ge(unsigned* p, unsigned tgt) {
    int gd = 0;
    while (__hip_atomic_load(p, __ATOMIC_ACQUIRE, __HIP_MEMORY_SCOPE_WORKGROUP) < tgt) {
        __builtin_amdgcn_s_sleep(1);
        if (++gd > (1 << 24)) break;
    }
}

// ---------------- lin_all = xs @ W_lin + b_lin for ALL 13 layers (fp16 out) ----------------
__global__ __launch_bounds__(256) void lin_kernel(
    const float* __restrict__ xs, const float* __restrict__ Wl,
    const float* __restrict__ bl, __half* __restrict__ lin)
{
    __shared__ float sA[64][68];
    __shared__ float sW[64][68];
    const int t = threadIdx.x;
    const size_t row0 = (size_t)blockIdx.x * 64;
    const int r4 = (t >> 4) << 2;
    const int c4 = (t & 15) << 2;

    float acc[4][4];
    #pragma unroll
    for (int i = 0; i < 4; ++i)
        #pragma unroll
        for (int j = 0; j < 4; ++j) acc[i][j] = 0.f;

    for (int kt = 0; kt < H_; kt += 64) {
        #pragma unroll
        for (int p = 0; p < 4; ++p) {
            int idx = t + 256 * p;
            int r = idx >> 4, cc = (idx & 15) << 2;
            *(float4*)&sA[r][cc] = *(const float4*)&xs[(row0 + r) * H_ + kt + cc];
            *(float4*)&sW[r][cc] = *(const float4*)&Wl[(size_t)(kt + r) * GG + cc];
        }
        __syncthreads();
        #pragma unroll 8
        for (int k = 0; k < 64; ++k) {
            float a0 = sA[r4 + 0][k], a1 = sA[r4 + 1][k], a2 = sA[r4 + 2][k], a3 = sA[r4 + 3][k];
            float4 w = *(const float4*)&sW[k][c4];
            acc[0][0] += a0 * w.x; acc[0][1] += a0 * w.y; acc[0][2] += a0 * w.z; acc[0][3] += a0 * w.w;
            acc[1][0] += a1 * w.x; acc[1][1] += a1 * w.y; acc[1][2] += a1 * w.z; acc[1][3] += a1 * w.w;
            acc[2][0] += a2 * w.x; acc[2][1] += a2 * w.y; acc[2][2] += a2 * w.z; acc[2][3] += a2 * w.w;
            acc[3][0] += a3 * w.x; acc[3][1] += a3 * w.y; acc[3][2] += a3 * w.z; acc[3][3] += a3 * w.w;
        }
        __syncthreads();
    }
    float4 bv = *(const float4*)&bl[c4];
    #pragma unroll
    for (int i = 0; i < 4; ++i) {
        F2H2 u;
        u.hh[0] = __floats2half2_rn(acc[i][0] + bv.x, acc[i][1] + bv.y);
        u.hh[1] = __floats2half2_rn(acc[i][2] + bv.z, acc[i][3] + bv.w);
        *(float2*)&lin[(row0 + r4 + i) * GG + c4] = u.f2;
    }
}

// ------- one block per batch: pipelined 13 x (LN+xp producers || bidir GRU scan) + classifier -------
__global__ __launch_bounds__(512) void chain_kernel(
    const __half* __restrict__ lin_all,
    const float* __restrict__ Wr_f, const float* __restrict__ b_f,
    const float* __restrict__ Wr_b, const float* __restrict__ b_b,
    const float* __restrict__ Wk_f, const float* __restrict__ Wk_b,
    const float* __restrict__ ln_g, const float* __restrict__ ln_b,
    const float* __restrict__ W_cls, const float* __restrict__ b_cls,
    float* __restrict__ out)
{
    extern __shared__ float sm[];
    float*    seqb   = sm;                          // [128][SEQ_ST] f32
    __half2*  wk2    = (__half2*)(sm + OFF_WK);     // [2][32][WK_ST] pre-scaled
    __half*   xph    = (__half*)(sm + OFF_XPH);     // [2][128][XPH_ST]
    __half2*  xt2all = (__half2*)(sm + OFF_XT2);    // 6 waves x [32][18]
    float*    hbf    = sm + OFF_HB;
    float*    hbb    = hbf + NU;
    unsigned* seq_blk = (unsigned*)(sm + OFF_FLG);  // [2][8]
    unsigned* gemcnt  = seq_blk + 16;               // [8]

    const int b = blockIdx.x;
    const int t = threadIdx.x;
    const int wave = t >> 6;
    const int lane = t & 63;
    const int v16 = lane & 15;
    const int b4 = (lane >> 4) & 1;
    const int b5 = (lane >> 5) & 1;
    const int ud = v16 + 16 * b5;

    for (int i = t; i < S_ * SEQ_ST; i += 512) seqb[i] = 0.f;
    if (t < 24) seq_blk[t] = 0u;
    // stage Wk with gate scaling folded in (z,r thirds: K1; h third: K2)
    for (int i = t; i < 2 * 32 * 96; i += 512) {
        const int d = i / 3072, rem = i - d * 3072, k2 = rem / 96, c = rem - k2 * 96;
        const float* W = d ? Wk_b : Wk_f;
        const float sc = (c >= 64) ? K2f : K1f;
        wk2[(d * 32 + k2) * WK_ST + c] =
            __floats2half2_rn(W[(2 * k2) * TU + c] * sc, W[(2 * k2 + 1) * TU + c] * sc);
    }

    // ---- scan-wave persistent state (waves 0=fwd, 1=bwd), scaled weights ----
    v2f wz[8], wr_[8], wh[8];
    float h_store = 0.f, h_dot = 0.f, rbz2 = 0.f, rbr2 = 0.f, rbh2 = 0.f;
    if (wave < 2) {
        const float* Wr   = wave ? Wr_b : Wr_f;
        const float* bias = wave ? b_b  : b_f;
        const int ex[8] = {0, 2, 7, 5, 15, 13, 8, 10};
        const int ey[8] = {1, 3, 6, 4, 14, 12, 9, 11};
        const int BB = 16 * b4;
        #pragma unroll
        for (int m = 0; m < 8; ++m) {
            const int jx = BB + (v16 ^ ex[m]), jy = BB + (v16 ^ ey[m]);
            wz[m]  = v2f{ K1f * Wr[jx * TU + ud],          K1f * Wr[jy * TU + ud] };
            wr_[m] = v2f{ K1f * Wr[jx * TU + NU + ud],     K1f * Wr[jy * TU + NU + ud] };
            wh[m]  = v2f{ K2f * Wr[jx * TU + 2 * NU + ud], K2f * Wr[jy * TU + 2 * NU + ud] };
        }
        rbz2 = 0.5f * K1f * bias[TU + ud];
        rbr2 = 0.5f * K1f * bias[TU + NU + ud];
        rbh2 = 0.5f * K2f * bias[TU + 2 * NU + ud];
    }

    __syncthreads();

    if (wave < 2) {
        // ================= SCAN WAVES =================
        const int dir = wave;
        const __half* xp = xph + dir * (S_ * XPH_ST);
        float* sq = seqb + dir * NU + (lane & 31);
        const int stp = dir ? -1 : 1;
        const bool wl = (lane < 32);
        const bool fix = (b4 != b5);

        for (int L = 0; L < L_; ++L) {
            unsigned dmask = 0;
            poll_ge(&gemcnt[7], (unsigned)(L + 1));
            dmask |= 1u << 7;
            int s = dir ? (S_ - 1) : 0;
            float xz = (float)xp[s * XPH_ST + ud];
            float xr = (float)xp[s * XPH_ST + 32 + ud];
            float xh = (float)xp[s * XPH_ST + 64 + ud];
            for (int st = 0; st < S_; ++st) {
                float nz = 0.f, nr = 0.f, nh = 0.f;
                if (st < S_ - 1) {
                    const int rp = s + stp;
                    const int g = chunk_of(rp);
                    if (!((dmask >> g) & 1u)) {
                        poll_ge(&gemcnt[g], (unsigned)(L + 1));
                        dmask |= 1u << g;
                    }
                    nz = (float)xp[rp * XPH_ST + ud];
                    nr = (float)xp[rp * XPH_ST + 32 + ud];
                    nh = (float)xp[rp * XPH_ST + 64 + ud];
                }
                // row-local butterfly
                v2f ro[8];
                ro[0].x = h_store;                ro[0].y = dppf<DPP_X1>(h_store);
                ro[1].x = dppf<DPP_X2>(ro[0].x);  ro[1].y = dppf<DPP_X2>(ro[0].y);
                ro[2].x = dppf<DPP_X7>(ro[0].x);  ro[2].y = dppf<DPP_X7>(ro[0].y);
                ro[3].x = dppf<DPP_X7>(ro[1].x);  ro[3].y = dppf<DPP_X7>(ro[1].y);
                ro[4].x = dppf<DPP_X15>(ro[0].x); ro[4].y = dppf<DPP_X15>(ro[0].y);
                ro[5].x = dppf<DPP_X15>(ro[1].x); ro[5].y = dppf<DPP_X15>(ro[1].y);
                ro[6].x = dppf<DPP_X15>(ro[2].x); ro[6].y = dppf<DPP_X15>(ro[2].y);
                ro[7].x = dppf<DPP_X15>(ro[3].x); ro[7].y = dppf<DPP_X15>(ro[3].y);

                // split half-dot chains (bias/x pre-halved; partner adds same)
                v2f aza = v2f{0.5f * xz + rbz2, 0.f}, azb = v2f{0.f, 0.f};
                v2f ara = v2f{0.5f * xr + rbr2, 0.f}, arb = v2f{0.f, 0.f};
                v2f aha = v2f{rbh2, 0.f},             ahb = v2f{0.f, 0.f};
                #pragma unroll
                for (int m = 0; m < 4; ++m) {
                    pkfma(aza, ro[m], wz[m]);      pkfma(azb, ro[m + 4], wz[m + 4]);
                    pkfma(ara, ro[m], wr_[m]);     pkfma(arb, ro[m + 4], wr_[m + 4]);
                    pkfma(aha, ro[m], wh[m]);      pkfma(ahb, ro[m + 4], wh[m + 4]);
                }
                v2f azs = aza + azb, ars = ara + arb, ahs = aha + ahb;
                const float pz = pairsum16(azs.x + azs.y);
                const float pr = pairsum16(ars.x + ars.y);
                const float ph = pairsum16(ahs.x + ahs.y);

                // exp2-based gates, raw rcp (no IEEE divide)
                const float z  = __builtin_amdgcn_rcpf(1.0f + __builtin_amdgcn_exp2f(-pz));
                const float r  = __builtin_amdgcn_rcpf(1.0f + __builtin_amdgcn_exp2f(-pr));
                const float tt = xh + r * ph;                     // pre-scaled by K2
                const float et = __builtin_amdgcn_exp2f(-tt);
                const float hh = (1.0f - et) * __builtin_amdgcn_rcpf(1.0f + et);
                const float hn_raw = hh + z * (h_dot - hh);
                h_dot = hn_raw;
                uv2 s32 = __builtin_amdgcn_permlane32_swap(
                    __float_as_uint(hn_raw), __float_as_uint(hn_raw), false, false);
                const float v32 = wl ? __uint_as_float(s32.y) : __uint_as_float(s32.x);
                h_store = fix ? v32 : hn_raw;
                if (wl) sq[s * SEQ_ST] = h_store;
                const bool pub = dir ? ((s & 15) == 0) : ((s & 15) == 15);
                if (pub && lane == 0)
                    __hip_atomic_store(&seq_blk[dir * 8 + (s >> 4)], (unsigned)(L + 1),
                                       __ATOMIC_RELEASE, __HIP_MEMORY_SCOPE_WORKGROUP);
                s += stp; xz = nz; xr = nr; xh = nh;
            }
        }
        if (wl) (dir ? hbb : hbf)[lane & 31] = h_store;
    } else {
        // ================= PRODUCER WAVES (6) =================
        const int w = wave - 2;
        __half2* xt2w = xt2all + w * 576;            // [32 k2][18]
        const int c4 = (lane & 15) << 2;
        const int g16 = lane >> 4;
        const int lr4 = lane & 3;
        const int cg = lane >> 2;
        const int dsel = cg >> 3;
        const int cc = (cg & 7) * 12;
        const float* bias0 = dsel ? b_b : b_f;
        const __half2* wkd = wk2 + dsel * 32 * WK_ST;
        __half* xpd = xph + dsel * (S_ * XPH_ST);
        float bsc[12];
        #pragma unroll
        for (int m = 0; m < 12; ++m)
            bsc[m] = bias0[cc + m] * ((cc + m >= 64) ? K2f : K1f);

        for (int L = 0; L < L_; ++L) {
            const __half* linb = lin_all + (size_t)(L * B_ + b) * S_ * GG;
            #pragma unroll 1
            for (int g = 0; g < 8; ++g) {
                if ((L * 8 + g) % 6 != w) continue;
                const int bl = (56 - 8 * g) >> 4;
                const int rA = 56 - 8 * g, rB = 64 + 8 * g;
                poll_ge(&seq_blk[bl], (unsigned)L);
                poll_ge(&seq_blk[7 - bl], (unsigned)L);
                poll_ge(&seq_blk[8 + bl], (unsigned)L);
                poll_ge(&seq_blk[8 + 7 - bl], (unsigned)L);

                // ---- LN: 16 rows, 4 passes of 4 (16-lane groups) ----
                #pragma unroll
                for (int p = 0; p < 4; ++p) {
                    const int lr = 4 * p + g16;
                    const int r = (lr < 8) ? (rA + lr) : (rB + lr - 8);
                    F2H2 lu; lu.f2 = *(const float2*)&linb[(size_t)r * GG + c4];
                    float4 sv = *(const float4*)&seqb[r * SEQ_ST + c4];
                    float2 l0 = __half22float2(lu.hh[0]);
                    float2 l1 = __half22float2(lu.hh[1]);
                    float v0 = l0.x + sv.x, v1 = l0.y + sv.y, v2 = l1.x + sv.z, v3 = l1.y + sv.w;
                    float s = v0 + v1 + v2 + v3;
                    #pragma unroll
                    for (int off = 1; off < 16; off <<= 1) s += __shfl_xor(s, off);
                    const float mean = s * 0.015625f;
                    const float d0 = v0 - mean, d1 = v1 - mean, d2 = v2 - mean, d3 = v3 - mean;
                    float q = d0 * d0 + d1 * d1 + d2 * d2 + d3 * d3;
                    #pragma unroll
                    for (int off = 1; off < 16; off <<= 1) q += __shfl_xor(q, off);
                    const float rstd = rsqrtf(q * 0.015625f + LN_EPS);
                    float4 gm = *(const float4*)&ln_g[c4];
                    float4 bt = *(const float4*)&ln_b[c4];
                    const float x0 = d0 * rstd * gm.x + bt.x;
                    const float x1 = d1 * rstd * gm.y + bt.y;
                    const float x2 = d2 * rstd * gm.z + bt.z;
                    const float x3 = d3 * rstd * gm.w + bt.w;
                    const int k2a = (lane & 15) << 1;
                    xt2w[(k2a + 0) * 18 + lr] = __floats2half2_rn(x0, x1);
                    xt2w[(k2a + 1) * 18 + lr] = __floats2half2_rn(x2, x3);
                }

                // ---- xp GEMM for the 16 rows (own xt2 buffer, fdot2) ----
                float acc[4][12];
                #pragma unroll
                for (int m = 0; m < 12; ++m) {
                    acc[0][m] = bsc[m]; acc[1][m] = bsc[m]; acc[2][m] = bsc[m]; acc[3][m] = bsc[m];
                }
                #pragma unroll 4
                for (int k2 = 0; k2 < 32; ++k2) {
                    FH2 x0, x1, x2, x3;
                    x0.hh = xt2w[k2 * 18 + lr4];
                    x1.hh = xt2w[k2 * 18 + lr4 + 4];
                    x2.hh = xt2w[k2 * 18 + lr4 + 8];
                    x3.hh = xt2w[k2 * 18 + lr4 + 12];
                    F4H8 wa, wb, wc;
                    wa.f4 = *(const float4*)&wkd[k2 * WK_ST + cc];
                    wb.f4 = *(const float4*)&wkd[k2 * WK_ST + cc + 4];
                    wc.f4 = *(const float4*)&wkd[k2 * WK_ST + cc + 8];
                    #pragma unroll
                    for (int m = 0; m < 4; ++m) {
                        acc[0][m]     = __builtin_amdgcn_fdot2(x0.h, wa.h[m], acc[0][m],     false);
                        acc[1][m]     = __builtin_amdgcn_fdot2(x1.h, wa.h[m], acc[1][m],     false);
                        acc[2][m]     = __builtin_amdgcn_fdot2(x2.h, wa.h[m], acc[2][m],     false);
                        acc[3][m]     = __builtin_amdgcn_fdot2(x3.h, wa.h[m], acc[3][m],     false);
                        acc[0][m + 4] = __builtin_amdgcn_fdot2(x0.h, wb.h[m], acc[0][m + 4], false);
                        acc[1][m + 4] = __builtin_amdgcn_fdot2(x1.h, wb.h[m], acc[1][m + 4], false);
                        acc[2][m + 4] = __builtin_amdgcn_fdot2(x2.h, wb.h[m], acc[2][m + 4], false);
                        acc[3][m + 4] = __builtin_amdgcn_fdot2(x3.h, wb.h[m], acc[3][m + 4], false);
                        acc[0][m + 8] = __builtin_amdgcn_fdot2(x0.h, wc.h[m], acc[0][m + 8], false);
                        acc[1][m + 8] = __builtin_amdgcn_fdot2(x1.h, wc.h[m], acc[1][m + 8], false);
                        acc[2][m + 8] = __builtin_amdgcn_fdot2(x2.h, wc.h[m], acc[2][m + 8], false);
                        acc[3][m + 8] = __builtin_amdgcn_fdot2(x3.h, wc.h[m], acc[3][m + 8], false);
                    }
                }
                #pragma unroll
                for (int i = 0; i < 4; ++i) {
                    const int lr = lr4 + 4 * i;
                    const int r = (lr < 8) ? (rA + lr) : (rB + lr - 8);
                    __half2* dst = (__half2*)&xpd[r * XPH_ST + cc];
                    #pragma unroll
                    for (int j = 0; j < 6; ++j)
                        dst[j] = __floats2half2_rn(acc[i][2 * j], acc[i][2 * j + 1]);
                }
                if (lane == 0)
                    __hip_atomic_store(&gemcnt[g], (unsigned)(L + 1),
                                       __ATOMIC_RELEASE, __HIP_MEMORY_SCOPE_WORKGROUP);
            }
        }
    }

    __syncthreads();
    if (t == 0) {
        float l0 = b_cls[0], l1 = b_cls[1];
        for (int j = 0; j < NU; ++j) {
            const float hf = hbf[j], hk = hbb[j];
            l0 += hf * W_cls[4 * j]     + hk * W_cls[4 * j + 2];
            l1 += hf * W_cls[4 * j + 1] + hk * W_cls[4 * j + 3];
        }
        const float m = fmaxf(l0, l1);
        const float e0 = __expf(l0 - m), e1 = __expf(l1 - m);
        const float inv = 1.0f / (e0 + e1);
        out[b * 2 + 0] = e0 * inv;
        out[b * 2 + 1] = e1 * inv;
    }
}

extern "C" void kernel_launch(void* const* d_in, const int* in_sizes, int n_in,
                              void* d_out, int out_size, void* d_ws, size_t ws_size,
                              hipStream_t stream) {
    const float* xs    = (const float*)d_in[0];
    const float* W_lin = (const float*)d_in[1];
    const float* b_lin = (const float*)d_in[2];
    const float* ln_g  = (const float*)d_in[3];
    const float* ln_b  = (const float*)d_in[4];
    const float* Wk_f  = (const float*)d_in[5];
    const float* Wr_f  = (const float*)d_in[6];
    const float* b_f   = (const float*)d_in[7];
    const float* Wk_b  = (const float*)d_in[8];
    const float* Wr_b  = (const float*)d_in[9];
    const float* b_b   = (const float*)d_in[10];
    const float* W_cls = (const float*)d_in[11];
    const float* b_cls = (const float*)d_in[12];
    float* out = (float*)d_out;

    __half* lin_all = (__half*)d_ws;   // 13*4096*64 fp16 = 6,815,744 B

    const int smem = SMEM_FLOATS * (int)sizeof(float);   // 125,824 B
    (void)hipFuncSetAttribute((const void*)chain_kernel,
                              hipFuncAttributeMaxDynamicSharedMemorySize, smem);

    lin_kernel<<<(L_ * B_ * S_) / 64, 256, 0, stream>>>(xs, W_lin, b_lin, lin_all);

    chain_kernel<<<B_, 512, smem, stream>>>(
        lin_all, Wr_f, b_f, Wr_b, b_b, Wk_f, Wk_b, ln_g, ln_b, W_cls, b_cls, out);
}